// Round 11
// baseline (1773.831 us; speedup 1.0000x reference)
//
#include <hip/hip_runtime.h>
#include <hip/hip_bf16.h>

#define NN 10000
#define EE 160000
#define GG 64
#define DD 480
#define HH 4
#define LLAYERS 6
#define DHD 120
#define NB_ 128
#define TSIZE 4096
#define DMAXT 5.5f
#define LSCALE (4095.0f/5.5f)

#define INV_DH 0.09128709291752768f
#define INV_SQRT_DEG 0.25335277f
#define INV_AVG_NODES (1.0f/18.03065905448718f)

typedef __attribute__((ext_vector_type(8))) short bf16x8;
typedef __attribute__((ext_vector_type(4))) float f32x4;
typedef __attribute__((ext_vector_type(8))) unsigned short u16x8;

__device__ __forceinline__ float b2f(unsigned short u){ return __uint_as_float(((unsigned)u)<<16); }
__device__ __forceinline__ unsigned short f2b(float f){
  unsigned u = __float_as_uint(f);
  return (unsigned short)((u + 0x7fffu + ((u>>16)&1u)) >> 16);
}
__device__ __forceinline__ float wsum(float v){
  #pragma unroll
  for (int off=32; off>0; off>>=1) v += __shfl_xor(v, off, 64);
  return v;
}
__device__ __forceinline__ void glds16(const void* g, void* l) {
  __builtin_amdgcn_global_load_lds((const __attribute__((address_space(1))) unsigned int*)g,
                                   (__attribute__((address_space(3))) unsigned int*)l, 16, 0, 0);
}

// ---------------- zero ----------------
__global__ __launch_bounds__(256) void zero_kernel(int* __restrict__ cnt, float* __restrict__ out){
  int i = blockIdx.x*256 + threadIdx.x;
  if (i < NN) cnt[i] = 0;
  if (i < GG) out[i] = 0.f;
}

// ---------------- x = atom_table[node_atom] ----------------
__global__ __launch_bounds__(256) void gather_x_kernel(const float* __restrict__ at,
    const int* __restrict__ atom, float* __restrict__ x){
  const int wid = threadIdx.x >> 6, lane = threadIdx.x & 63;
  for (int n = blockIdx.x*4 + wid; n < NN; n += gridDim.x*4) {
    int a = atom[n];
    if (lane < 60) {
      const float4* src = (const float4*)(at + (size_t)a*DD + lane*8);
      float4* dst = (float4*)(x + (size_t)n*DD + lane*8);
      dst[0] = src[0]; dst[1] = src[1];
    }
  }
}

// ---------------- edge geometry ----------------
__global__ __launch_bounds__(256) void edge_geom_kernel(const float* __restrict__ pos,
    const int* __restrict__ esrc, const int* __restrict__ edst,
    float* __restrict__ sh, float* __restrict__ dedge){
  const int e = blockIdx.x*256 + threadIdx.x;
  if (e >= EE) return;
  int s = esrc[e], d = edst[e];
  float vx = pos[s*3+0]-pos[d*3+0];
  float vy = pos[s*3+1]-pos[d*3+1];
  float vz = pos[s*3+2]-pos[d*3+2];
  float rr = sqrtf(vx*vx+vy*vy+vz*vz);
  dedge[e] = rr;
  float r = rr + 1e-12f;
  float x = vx/r, y = vy/r, z = vz/r;
  const float s3 = 1.7320508075688772f;
  const float s5 = 2.23606797749979f;
  const float s15 = 3.872983346207417f;
  float* o = sh + (size_t)e*9;
  o[0] = 1.f;
  o[1] = s3*x; o[2] = s3*y; o[3] = s3*z;
  o[4] = s15*x*y; o[5] = s15*y*z;
  o[6] = 0.5f*s5*(3.f*z*z-1.f);
  o[7] = s15*x*z;
  o[8] = 0.5f*s15*(x*x-y*y);
}

// ---------------- sort by dst ----------------
__global__ __launch_bounds__(256) void hist_kernel(const int* __restrict__ edst, int* __restrict__ cnt){
  int e = blockIdx.x*256 + threadIdx.x;
  if (e < EE) atomicAdd(&cnt[edst[e]], 1);
}

__global__ __launch_bounds__(1024) void scan_kernel(const int* __restrict__ cnt,
    int* __restrict__ row_ptr, int* __restrict__ cursor){
  __shared__ int sd[1024];
  __shared__ int s_carry;
  if (threadIdx.x == 0) s_carry = 0;
  __syncthreads();
  for (int base = 0; base < NN; base += 1024) {
    int i = base + threadIdx.x;
    int v = (i < NN) ? cnt[i] : 0;
    sd[threadIdx.x] = v;
    __syncthreads();
    for (int off = 1; off < 1024; off <<= 1) {
      int t = 0;
      if ((int)threadIdx.x >= off) t = sd[threadIdx.x - off];
      __syncthreads();
      sd[threadIdx.x] += t;
      __syncthreads();
    }
    int incl = sd[threadIdx.x];
    int carry = s_carry;
    if (i < NN) { row_ptr[i] = carry + incl - v; cursor[i] = carry + incl - v; }
    __syncthreads();
    if (threadIdx.x == 1023) s_carry = carry + incl;
    __syncthreads();
  }
  if (threadIdx.x == 0) row_ptr[NN] = s_carry;
}

__global__ __launch_bounds__(256) void scatter_kernel(const int* __restrict__ esrc,
    const int* __restrict__ edst, int* __restrict__ cursor,
    int* __restrict__ eid, int* __restrict__ srcs){
  int e = blockIdx.x*256 + threadIdx.x;
  if (e < EE) {
    int n = edst[e];
    int p = atomicAdd(&cursor[n], 1);
    eid[p] = e;
    srcs[p] = esrc[e];
  }
}

// ---------------- gate/g0 lookup tables ----------------
__global__ __launch_bounds__(1024) void table_kernel(
    const float* __restrict__ Wd1, const float* __restrict__ Wd2, const float* __restrict__ Wd3,
    const float* __restrict__ W1, const float* __restrict__ W2, const float* __restrict__ W3,
    float* __restrict__ Tg, float* __restrict__ Tl) {
  const int chain = blockIdx.y;
  const float *A1, *A2, *A3; int NC;
  if (chain == 0) { A1 = Wd1; A2 = Wd2; A3 = Wd3; NC = 1; }
  else { int l = chain-1; A1 = W1 + (size_t)l*128*64; A2 = W2 + (size_t)l*64*64; A3 = W3 + (size_t)l*64*4; NC = 4; }
  __shared__ float W1s[128*64];
  __shared__ float W2s[64*64];
  __shared__ float W3s[64*4];
  for (int i = threadIdx.x; i < 128*64; i += 1024) W1s[i] = A1[i];
  for (int i = threadIdx.x; i < 64*64; i += 1024) W2s[i] = A2[i];
  for (int i = threadIdx.x; i < 64*4; i += 1024) W3s[i] = (i < 64*NC) ? A3[i] : 0.f;
  __syncthreads();
  const int wid = threadIdx.x >> 6, lane = threadIdx.x & 63;
  const int t = blockIdx.x*16 + wid;
  const float d = (float)t * (DMAXT/(float)(TSIZE-1));
  const float cstep = 5.0f/127.0f;
  int jc = (int)(d / cstep + 0.5f);
  int j0 = jc - 8; if (j0 < 0) j0 = 0;
  int j1 = jc + 8; if (j1 > 127) j1 = 127;
  float t1 = 0.f;
  for (int j = j0; j <= j1; ++j) {
    float z = (d - (float)j*cstep) * (128.0f/5.0f);
    float f = __expf(-z*z);
    t1 += f * W1s[j*64 + lane];
  }
  t1 = t1 / (1.f + __expf(-t1));
  float t2 = 0.f;
  #pragma unroll 4
  for (int c = 0; c < 64; ++c) {
    float bc = __shfl(t1, c);
    t2 += bc * W2s[c*64 + lane];
  }
  t2 = t2 / (1.f + __expf(-t2));
  if (chain == 0) {
    float o = wsum(t2 * W3s[lane]);
    if (lane == 0) Tg[t] = o;
  } else {
    #pragma unroll
    for (int nc = 0; nc < 4; ++nc) {
      float o = wsum(t2 * W3s[lane*4 + nc]);
      if (lane == 0) Tl[((size_t)(chain-1)*TSIZE + t)*4 + nc] = o;
    }
  }
}

__device__ __forceinline__ float lookup1(const float* __restrict__ Tg, float d) {
  float u = d * LSCALE;
  if (u >= (float)(TSIZE-1)) return 0.f;
  int i = (int)u; float fr = u - (float)i;
  float a = Tg[i], b = Tg[i+1];
  return a + fr*(b-a);
}

// ---------------- weight transpose+convert ----------------
__global__ __launch_bounds__(256) void transpose_w_kernel(const float* __restrict__ W,
    __hip_bfloat16* __restrict__ Wt, int K, int N, int Npad,
    long long lstrideW, long long lstrideT) {
  __shared__ float T[32][33];
  const int l = blockIdx.z;
  W  += (size_t)l*lstrideW;
  Wt += (size_t)l*lstrideT;
  const int k0 = blockIdx.y*32, n0 = blockIdx.x*32;
  const int tx = threadIdx.x & 31, ty = threadIdx.x >> 5;
  #pragma unroll
  for (int r = 0; r < 32; r += 8) {
    int k = k0 + ty + r, n = n0 + tx;
    T[ty+r][tx] = (k < K && n < N) ? W[(size_t)k*N + n] : 0.f;
  }
  __syncthreads();
  #pragma unroll
  for (int r = 0; r < 32; r += 8) {
    int n = n0 + ty + r, k = k0 + tx;
    if (n < Npad && k < K)
      ((unsigned short*)Wt)[(size_t)n*K + k] = f2b(T[tx][ty+r]);
  }
}

// ---------------- bf16 MFMA GEMM: tile 128x128x32, 8 waves, double-buffered ----------------
// OUT: 1=bf16 (Cb0), 2=QKV 3-way bf16 (512-col segments)
template<int SILU, int OUT>
__global__ __launch_bounds__(512) void gemm_bf16_kernel(
    const __hip_bfloat16* __restrict__ A, const __hip_bfloat16* __restrict__ Bt,
    __hip_bfloat16* __restrict__ Cb0, __hip_bfloat16* __restrict__ Cb1,
    __hip_bfloat16* __restrict__ Cb2,
    int M, int K, int Nc) {
  __shared__ char smem[32768];
  const int tid = threadIdx.x;
  const int lane = tid & 63, wid = tid >> 6;
  const int wm = wid >> 2, wn = wid & 3;
  const long long m0 = (long long)blockIdx.y * 128;
  const int n0 = blockIdx.x * 128;

  const int skhi = wid >> 1, srow = (wid & 1)*64 + lane;
  long long gra = m0 + srow; if (gra >= M) gra = M - 1;
  const __hip_bfloat16* aptr = A + gra * (size_t)K + skhi*8;
  const __hip_bfloat16* bptr = Bt + (size_t)(n0 + srow) * K + skhi*8;
  const int stoff = (skhi*128 + srow)*16;

  f32x4 acc[4][2];
  #pragma unroll
  for (int i = 0; i < 4; ++i)
    #pragma unroll
    for (int j = 0; j < 2; ++j)
      acc[i][j] = (f32x4){0.f,0.f,0.f,0.f};

  const int lr = lane & 15, lkh = lane >> 4;

  glds16(aptr, smem + stoff);
  glds16(bptr, smem + 8192 + stoff);
  __syncthreads();

  int cur = 0;
  for (int kt = 0; kt < K; kt += 32) {
    const int nxt = cur ^ 1;
    if (kt + 32 < K) {
      glds16(aptr + kt + 32, smem + nxt*16384 + stoff);
      glds16(bptr + kt + 32, smem + nxt*16384 + 8192 + stoff);
    }
    const char* AsB = smem + cur*16384;
    const char* BsB = AsB + 8192;
    bf16x8 afr[4], bfr[2];
    #pragma unroll
    for (int fm = 0; fm < 4; ++fm)
      afr[fm] = *reinterpret_cast<const bf16x8*>(AsB + (lkh*128 + wm*64 + fm*16 + lr)*16);
    #pragma unroll
    for (int fn = 0; fn < 2; ++fn)
      bfr[fn] = *reinterpret_cast<const bf16x8*>(BsB + (lkh*128 + wn*32 + fn*16 + lr)*16);
    #pragma unroll
    for (int fm = 0; fm < 4; ++fm)
      #pragma unroll
      for (int fn = 0; fn < 2; ++fn)
        acc[fm][fn] = __builtin_amdgcn_mfma_f32_16x16x32_bf16(afr[fm], bfr[fn], acc[fm][fn], 0, 0, 0);
    asm volatile("s_waitcnt vmcnt(0)" ::: "memory");
    asm volatile("s_barrier" ::: "memory");
    cur = nxt;
  }

  const int seg = n0 >> 9;
  const int c0 = (OUT == 2) ? (n0 & 511) : n0;
  unsigned short* qdst = (unsigned short*)Cb0;
  if (OUT == 2) qdst = (unsigned short*)(seg == 0 ? Cb0 : (seg == 1 ? Cb1 : Cb2));
  #pragma unroll
  for (int fm = 0; fm < 4; ++fm) {
    #pragma unroll
    for (int fn = 0; fn < 2; ++fn) {
      #pragma unroll
      for (int j = 0; j < 4; ++j) {
        long long r = m0 + wm*64 + fm*16 + lkh*4 + j;
        int c = c0 + wn*32 + fn*16 + lr;
        if (r < M && c < Nc) {
          float v = acc[fm][fn][j];
          if (SILU) v = v / (1.f + __expf(-v));
          qdst[r*(size_t)Nc + c] = f2b(v);
        }
      }
    }
  }
}

// ---------------- bf16 MFMA GEMM: tile 128x64x32, 4 waves, double-buffered (narrow N) ----------------
template<int SILU>
__global__ __launch_bounds__(256) void gemm64_bf16_kernel(
    const __hip_bfloat16* __restrict__ A, const __hip_bfloat16* __restrict__ Bt,
    __hip_bfloat16* __restrict__ Cb, int M, int K, int Nc) {
  __shared__ char smem[24576];   // 2 × (A 8KB + B 4KB)
  const int tid = threadIdx.x;
  const int lane = tid & 63, wid = tid >> 6;      // 4 waves
  const int wm = wid >> 1, wn = wid & 1;          // wave tile 64 rows × 32 cols
  const long long m0 = (long long)blockIdx.y * 128;
  const int n0 = blockIdx.x * 64;

  // A staging: 2 issues/wave: khi = (wid>>1) + 2*i, row = (wid&1)*64+lane
  const int srow = (wid & 1)*64 + lane;
  long long gra = m0 + srow; if (gra >= M) gra = M - 1;
  const __hip_bfloat16* aptr = A + gra * (size_t)K;
  const int khiA0 = wid >> 1, khiA1 = 2 + (wid >> 1);
  const int aoff0 = (khiA0*128 + srow)*16;
  const int aoff1 = (khiA1*128 + srow)*16;
  // B staging: 1 issue/wave: khi = wid, col = lane
  const __hip_bfloat16* bptr = Bt + (size_t)(n0 + lane) * K + wid*8;
  const int boff = (wid*64 + lane)*16;

  f32x4 acc[4][2];
  #pragma unroll
  for (int i = 0; i < 4; ++i)
    #pragma unroll
    for (int j = 0; j < 2; ++j)
      acc[i][j] = (f32x4){0.f,0.f,0.f,0.f};

  const int lr = lane & 15, lkh = lane >> 4;

  glds16(aptr + khiA0*8, smem + aoff0);
  glds16(aptr + khiA1*8, smem + aoff1);
  glds16(bptr, smem + 8192 + boff);
  __syncthreads();

  int cur = 0;
  for (int kt = 0; kt < K; kt += 32) {
    const int nxt = cur ^ 1;
    if (kt + 32 < K) {
      glds16(aptr + kt + 32 + khiA0*8, smem + nxt*12288 + aoff0);
      glds16(aptr + kt + 32 + khiA1*8, smem + nxt*12288 + aoff1);
      glds16(bptr + kt + 32, smem + nxt*12288 + 8192 + boff);
    }
    const char* AsB = smem + cur*12288;
    const char* BsB = AsB + 8192;
    bf16x8 afr[4], bfr[2];
    #pragma unroll
    for (int fm = 0; fm < 4; ++fm)
      afr[fm] = *reinterpret_cast<const bf16x8*>(AsB + (lkh*128 + wm*64 + fm*16 + lr)*16);
    #pragma unroll
    for (int fn = 0; fn < 2; ++fn)
      bfr[fn] = *reinterpret_cast<const bf16x8*>(BsB + (lkh*64 + wn*32 + fn*16 + lr)*16);
    #pragma unroll
    for (int fm = 0; fm < 4; ++fm)
      #pragma unroll
      for (int fn = 0; fn < 2; ++fn)
        acc[fm][fn] = __builtin_amdgcn_mfma_f32_16x16x32_bf16(afr[fm], bfr[fn], acc[fm][fn], 0, 0, 0);
    asm volatile("s_waitcnt vmcnt(0)" ::: "memory");
    asm volatile("s_barrier" ::: "memory");
    cur = nxt;
  }

  #pragma unroll
  for (int fm = 0; fm < 4; ++fm) {
    #pragma unroll
    for (int fn = 0; fn < 2; ++fn) {
      #pragma unroll
      for (int j = 0; j < 4; ++j) {
        long long r = m0 + wm*64 + fm*16 + lkh*4 + j;
        int c = n0 + wn*32 + fn*16 + lr;
        if (r < M && c < Nc) {
          float v = acc[fm][fn][j];
          if (SILU) v = v / (1.f + __expf(-v));
          ((unsigned short*)Cb)[r*(size_t)Nc + c] = f2b(v);
        }
      }
    }
  }
}

// ---------------- deg ----------------
__global__ __launch_bounds__(256) void deg_kernel(const float* __restrict__ dedge,
    const float* __restrict__ sh, const float* __restrict__ Tg,
    const int* __restrict__ row_ptr, const int* __restrict__ eid,
    const float* __restrict__ Wdeg, float* __restrict__ x, __hip_bfloat16* __restrict__ xb) {
  const int wid = threadIdx.x >> 6, lane = threadIdx.x & 63;
  for (int n = blockIdx.x*4 + wid; n < NN; n += gridDim.x*4) {
    const int e0 = row_ptr[n], e1 = row_ptr[n+1];
    float s9[9] = {0,0,0,0,0,0,0,0,0};
    for (int p = e0 + lane; p < e1; p += 64) {
      int e = eid[p];
      float g = lookup1(Tg, dedge[e]);
      const float* srow = sh + (size_t)e*9;
      #pragma unroll
      for (int s = 0; s < 9; ++s) s9[s] += g*srow[s];
    }
    #pragma unroll
    for (int s = 0; s < 9; ++s) s9[s] = wsum(s9[s]);
    #pragma unroll
    for (int r = 0; r < 8; ++r) {
      int d = lane + (r<<6);
      if (d < DD) {
        float acc = 0.f;
        #pragma unroll
        for (int s = 0; s < 9; ++s) acc += s9[s]*Wdeg[s*DD + d];
        float vv = x[(size_t)n*DD + d] + acc * INV_SQRT_DEG;
        x[(size_t)n*DD + d] = vv;
        ((unsigned short*)xb)[(size_t)n*DD + d] = f2b(vv);
      }
    }
  }
}

// ---------------- P[n,h,s] ----------------
__global__ __launch_bounds__(256) void p_kernel(const __hip_bfloat16* __restrict__ xq,
    const float* __restrict__ Wsh_l, float* __restrict__ P) {
  const int wid = threadIdx.x >> 6, lane = threadIdx.x & 63;
  for (int n = blockIdx.x*4 + wid; n < NN; n += gridDim.x*4) {
    if (lane < 36) {
      int h = lane/9, s = lane%9;
      const unsigned short* q = (const unsigned short*)(xq + (size_t)n*DD + h*DHD);
      const float* w = Wsh_l + s*DD + h*DHD;
      float acc = 0.f;
      #pragma unroll
      for (int db = 0; db < 15; ++db) {
        u16x8 v = *reinterpret_cast<const u16x8*>(q + db*8);
        #pragma unroll
        for (int j = 0; j < 8; ++j) acc += b2f(v[j])*w[db*8+j];
      }
      P[(size_t)n*36 + lane] = acc;
    }
  }
}

// ---------------- per-edge logit coefficients ----------------
__global__ __launch_bounds__(256) void coef_kernel(
    const int* __restrict__ eid, const int* __restrict__ edst,
    const float* __restrict__ sh, const float* __restrict__ dedge,
    const float* __restrict__ Tl, const float* __restrict__ P,
    float2* __restrict__ sb) {
  const int p = blockIdx.x*256 + threadIdx.x;
  if (p >= EE) return;
  const int e = eid[p];
  const int n = edst[e];
  const float* srow = sh + (size_t)e*9;
  float s0 = srow[0], s1 = srow[1], s2 = srow[2], s3 = srow[3], s4 = srow[4];
  float s5 = srow[5], s6 = srow[6], s7 = srow[7], s8 = srow[8];
  const float* Pn = P + (size_t)n*36;
  float g[4];
  {
    float u = dedge[e] * LSCALE;
    if (u >= (float)(TSIZE-1)) { g[0]=g[1]=g[2]=g[3]=0.f; }
    else {
      int ti = (int)u; float fr = u - (float)ti;
      const float4 ga = *reinterpret_cast<const float4*>(Tl + ti*4);
      const float4 gb = *reinterpret_cast<const float4*>(Tl + ti*4 + 4);
      g[0] = ga.x + fr*(gb.x-ga.x); g[1] = ga.y + fr*(gb.y-ga.y);
      g[2] = ga.z + fr*(gb.z-ga.z); g[3] = ga.w + fr*(gb.w-ga.w);
    }
  }
  #pragma unroll
  for (int h = 0; h < 4; ++h) {
    const float* Ph = Pn + h*9;
    float lp = s0*Ph[0]+s1*Ph[1]+s2*Ph[2]+s3*Ph[3]+s4*Ph[4]
             + s5*Ph[5]+s6*Ph[6]+s7*Ph[7]+s8*Ph[8];
    float sc = INV_DH * g[h];
    sb[(size_t)p*4 + h] = make_float2(sc, lp*sc);
  }
}

// ---------------- fused attention: 1 node/wave ----------------
__global__ __launch_bounds__(256) void attn_kernel(
    const __hip_bfloat16* __restrict__ xq, const __hip_bfloat16* __restrict__ xk,
    const __hip_bfloat16* __restrict__ xv, const float2* __restrict__ sb,
    const int* __restrict__ row_ptr, const int* __restrict__ srcs,
    __hip_bfloat16* __restrict__ aggout) {
  const int wid = threadIdx.x >> 6, lane = threadIdx.x & 63;
  __shared__ float l_s[4][64][4];
  __shared__ int   src_sh[4][64];
  float (*ls)[4] = l_s[wid];
  int* srcS = src_sh[wid];
  const int hh = lane >> 4, li = lane & 15;
  const int hd = (lane < 60) ? (lane/15) : 3;
  const unsigned short* xkp = (const unsigned short*)xk;
  const unsigned short* xvp = (const unsigned short*)xv;
  const int doff = hh*DHD + li*8;
  for (int n = blockIdx.x*4 + wid; n < NN; n += gridDim.x*4) {
    const int e0 = row_ptr[n], e1 = row_ptr[n+1];
    float qf[8] = {0,0,0,0,0,0,0,0};
    if (li < 15) {
      u16x8 v = *reinterpret_cast<const u16x8*>((const unsigned short*)xq + (size_t)n*DD + doff);
      #pragma unroll
      for (int j = 0; j < 8; ++j) qf[j] = b2f(v[j]);
    }
    float m_reg = -1e30f, den_reg = 0.f;
    float agg[8] = {0,0,0,0,0,0,0,0};
    for (int c0 = e0; c0 < e1; c0 += 64) {
      const int cn = min(64, e1 - c0);
      if (lane < cn) srcS[lane] = srcs[c0 + lane];
      asm volatile("s_waitcnt lgkmcnt(0)" ::: "memory");
      int i = 0;
      for (; i + 4 <= cn; i += 4) {
        int sA = srcS[i], sB = srcS[i+1], sC = srcS[i+2], sD = srcS[i+3];
        float a0 = 0.f, a1 = 0.f, a2 = 0.f, a3 = 0.f;
        if (li < 15) {
          u16x8 k0 = *reinterpret_cast<const u16x8*>(xkp + (size_t)sA*DD + doff);
          u16x8 k1 = *reinterpret_cast<const u16x8*>(xkp + (size_t)sB*DD + doff);
          u16x8 k2 = *reinterpret_cast<const u16x8*>(xkp + (size_t)sC*DD + doff);
          u16x8 k3 = *reinterpret_cast<const u16x8*>(xkp + (size_t)sD*DD + doff);
          #pragma unroll
          for (int j = 0; j < 8; ++j) {
            a0 += qf[j]*b2f(k0[j]);
            a1 += qf[j]*b2f(k1[j]);
            a2 += qf[j]*b2f(k2[j]);
            a3 += qf[j]*b2f(k3[j]);
          }
        }
        #pragma unroll
        for (int off = 1; off < 16; off <<= 1) {
          a0 += __shfl_xor(a0, off, 64);
          a1 += __shfl_xor(a1, off, 64);
          a2 += __shfl_xor(a2, off, 64);
          a3 += __shfl_xor(a3, off, 64);
        }
        if (li == 0) {
          float2 cA = sb[(size_t)(c0+i+0)*4 + hh];
          float2 cB = sb[(size_t)(c0+i+1)*4 + hh];
          float2 cC = sb[(size_t)(c0+i+2)*4 + hh];
          float2 cD = sb[(size_t)(c0+i+3)*4 + hh];
          ls[i+0][hh] = a0*cA.x + cA.y;
          ls[i+1][hh] = a1*cB.x + cB.y;
          ls[i+2][hh] = a2*cC.x + cC.y;
          ls[i+3][hh] = a3*cD.x + cD.y;
        }
      }
      for (; i < cn; ++i) {
        int sA = srcS[i];
        float a0 = 0.f;
        if (li < 15) {
          u16x8 k0 = *reinterpret_cast<const u16x8*>(xkp + (size_t)sA*DD + doff);
          #pragma unroll
          for (int j = 0; j < 8; ++j) a0 += qf[j]*b2f(k0[j]);
        }
        #pragma unroll
        for (int off = 1; off < 16; off <<= 1) a0 += __shfl_xor(a0, off, 64);
        if (li == 0) {
          float2 cA = sb[(size_t)(c0+i)*4 + hh];
          ls[i][hh] = a0*cA.x + cA.y;
        }
      }
      asm volatile("s_waitcnt lgkmcnt(0)" ::: "memory");
      const int h = lane & 3, i0 = lane >> 2;
      float cm = -1e30f;
      for (int i2 = i0; i2 < cn; i2 += 16) cm = fmaxf(cm, ls[i2][h]);
      #pragma unroll
      for (int off = 4; off < 64; off <<= 1) cm = fmaxf(cm, __shfl_xor(cm, off, 64));
      const float newm = fmaxf(m_reg, cm);
      const float f = __expf(m_reg - newm);
      float cs = 0.f;
      for (int i2 = i0; i2 < cn; i2 += 16) {
        float a = __expf(ls[i2][h] - newm);
        ls[i2][h] = a;
        cs += a;
      }
      #pragma unroll
      for (int off = 4; off < 64; off <<= 1) cs += __shfl_xor(cs, off, 64);
      m_reg = newm;
      den_reg = den_reg*f + cs;
      asm volatile("s_waitcnt lgkmcnt(0)" ::: "memory");
      const float fh = __shfl(f, hd);
      #pragma unroll
      for (int j = 0; j < 8; ++j) agg[j] *= fh;
      i = 0;
      for (; i + 4 <= cn; i += 4) {
        int sA = srcS[i], sB = srcS[i+1], sC = srcS[i+2], sD = srcS[i+3];
        float a0 = ls[i][hd], a1 = ls[i+1][hd], a2 = ls[i+2][hd], a3 = ls[i+3][hd];
        if (lane < 60) {
          u16x8 v0 = *reinterpret_cast<const u16x8*>(xvp + (size_t)sA*DD + lane*8);
          u16x8 v1 = *reinterpret_cast<const u16x8*>(xvp + (size_t)sB*DD + lane*8);
          u16x8 v2 = *reinterpret_cast<const u16x8*>(xvp + (size_t)sC*DD + lane*8);
          u16x8 v3 = *reinterpret_cast<const u16x8*>(xvp + (size_t)sD*DD + lane*8);
          #pragma unroll
          for (int j = 0; j < 8; ++j)
            agg[j] += a0*b2f(v0[j]) + a1*b2f(v1[j]) + a2*b2f(v2[j]) + a3*b2f(v3[j]);
        }
      }
      for (; i < cn; ++i) {
        int sA = srcS[i];
        float a0 = ls[i][hd];
        if (lane < 60) {
          u16x8 v0 = *reinterpret_cast<const u16x8*>(xvp + (size_t)sA*DD + lane*8);
          #pragma unroll
          for (int j = 0; j < 8; ++j) agg[j] += a0*b2f(v0[j]);
        }
      }
    }
    const float dh2 = __shfl(den_reg, hd);
    if (lane < 60) {
      const float sc = INV_SQRT_DEG / (dh2 + 1e-12f);
      u16x8 o;
      #pragma unroll
      for (int j = 0; j < 8; ++j) o[j] = f2b(agg[j]*sc);
      *reinterpret_cast<u16x8*>((unsigned short*)aggout + (size_t)n*DD + lane*8) = o;
    }
  }
}

// ---------------- residual + LayerNorm: x = LN(x + t(bf16)); xb = bf16(x) ----------------
__global__ __launch_bounds__(256) void ln_kernel(float* __restrict__ x,
    const __hip_bfloat16* __restrict__ tb, __hip_bfloat16* __restrict__ xb) {
  const int wid = threadIdx.x >> 6, lane = threadIdx.x & 63;
  for (int n = blockIdx.x*4 + wid; n < NN; n += gridDim.x*4) {
    float4 a0 = make_float4(0,0,0,0), a1 = make_float4(0,0,0,0);
    float s = 0.f, s2 = 0.f;
    if (lane < 60) {
      const float4* xp = (const float4*)(x + (size_t)n*DD + lane*8);
      u16x8 tv = *reinterpret_cast<const u16x8*>((const unsigned short*)tb + (size_t)n*DD + lane*8);
      a0 = xp[0]; a1 = xp[1];
      a0.x += b2f(tv[0]); a0.y += b2f(tv[1]); a0.z += b2f(tv[2]); a0.w += b2f(tv[3]);
      a1.x += b2f(tv[4]); a1.y += b2f(tv[5]); a1.z += b2f(tv[6]); a1.w += b2f(tv[7]);
      s  = a0.x+a0.y+a0.z+a0.w + a1.x+a1.y+a1.z+a1.w;
      s2 = a0.x*a0.x+a0.y*a0.y+a0.z*a0.z+a0.w*a0.w
         + a1.x*a1.x+a1.y*a1.y+a1.z*a1.z+a1.w*a1.w;
    }
    s = wsum(s); s2 = wsum(s2);
    const float mu = s * (1.f/(float)DD);
    const float var = s2 * (1.f/(float)DD) - mu*mu;
    const float rs = rsqrtf(var + 1e-5f);
    if (lane < 60) {
      float4* xp = (float4*)(x + (size_t)n*DD + lane*8);
      a0.x = (a0.x-mu)*rs; a0.y = (a0.y-mu)*rs; a0.z = (a0.z-mu)*rs; a0.w = (a0.w-mu)*rs;
      a1.x = (a1.x-mu)*rs; a1.y = (a1.y-mu)*rs; a1.z = (a1.z-mu)*rs; a1.w = (a1.w-mu)*rs;
      xp[0] = a0; xp[1] = a1;
      u16x8 o;
      o[0]=f2b(a0.x); o[1]=f2b(a0.y); o[2]=f2b(a0.z); o[3]=f2b(a0.w);
      o[4]=f2b(a1.x); o[5]=f2b(a1.y); o[6]=f2b(a1.z); o[7]=f2b(a1.w);
      *reinterpret_cast<u16x8*>((unsigned short*)xb + (size_t)n*DD + lane*8) = o;
    }
  }
}

// ---------------- final: LDS-staged per-group partials ----------------
__global__ __launch_bounds__(256) void h2_kernel(const __hip_bfloat16* __restrict__ tb,
    const float* __restrict__ Wh2, const int* __restrict__ batch, float* __restrict__ out) {
  __shared__ float part[GG];
  for (int i = threadIdx.x; i < GG; i += 256) part[i] = 0.f;
  __syncthreads();
  const int wid = threadIdx.x >> 6, lane = threadIdx.x & 63;
  const int per_block = (NN + gridDim.x - 1) / gridDim.x;
  const int n0 = blockIdx.x * per_block;
  const int n1 = min(NN, n0 + per_block);
  for (int n = n0 + wid; n < n1; n += 4) {
    float s = 0.f;
    if (lane < 60) {
      u16x8 tv = *reinterpret_cast<const u16x8*>((const unsigned short*)tb + (size_t)n*DD + lane*8);
      const float4* wp = (const float4*)(Wh2 + lane*8);
      float4 w0 = wp[0], w1 = wp[1];
      s = b2f(tv[0])*w0.x + b2f(tv[1])*w0.y + b2f(tv[2])*w0.z + b2f(tv[3])*w0.w
        + b2f(tv[4])*w1.x + b2f(tv[5])*w1.y + b2f(tv[6])*w1.z + b2f(tv[7])*w1.w;
    }
    s = wsum(s);
    if (lane == 0) atomicAdd(&part[batch[n]], s * INV_AVG_NODES);
  }
  __syncthreads();
  for (int i = threadIdx.x; i < GG; i += 256) {
    float v = part[i];
    if (v != 0.f) atomicAdd(&out[i], v);
  }
}

extern "C" void kernel_launch(void* const* d_in, const int* in_sizes, int n_in,
                              void* d_out, int out_size, void* d_ws, size_t ws_size,
                              hipStream_t stream) {
  const float* pos        = (const float*)d_in[0];
  const int*   node_atom  = (const int*)  d_in[1];
  const int*   edge_src   = (const int*)  d_in[2];
  const int*   edge_dst   = (const int*)  d_in[3];
  const int*   batch      = (const int*)  d_in[4];
  const float* atom_table = (const float*)d_in[5];
  const float* Wdeg       = (const float*)d_in[6];
  const float* Wd1        = (const float*)d_in[7];
  const float* Wd2        = (const float*)d_in[8];
  const float* Wd3        = (const float*)d_in[9];
  const float* Wq         = (const float*)d_in[10];
  const float* Wk         = (const float*)d_in[11];
  const float* Wv         = (const float*)d_in[12];
  const float* Wsh        = (const float*)d_in[13];
  const float* W1         = (const float*)d_in[14];
  const float* W2         = (const float*)d_in[15];
  const float* W3         = (const float*)d_in[16];
  const float* Wo         = (const float*)d_in[17];
  const float* Wf1        = (const float*)d_in[18];
  const float* Wf2        = (const float*)d_in[19];
  const float* Wh1        = (const float*)d_in[20];
  const float* Wh2        = (const float*)d_in[21];
  float* out = (float*)d_out;
  char*  wsb = (char*)d_ws;

  size_t off = 0;
  auto alloc = [&](size_t bytes) { size_t o = off; off += (bytes + 255) & ~(size_t)255; return o; };
  float*  x      = (float*) (wsb + alloc((size_t)NN*DD*4));
  __hip_bfloat16* xb   = (__hip_bfloat16*)(wsb + alloc((size_t)NN*DD*2));
  __hip_bfloat16* xq   = (__hip_bfloat16*)(wsb + alloc((size_t)NN*DD*2));
  __hip_bfloat16* xk   = (__hip_bfloat16*)(wsb + alloc((size_t)NN*DD*2));
  __hip_bfloat16* xv   = (__hip_bfloat16*)(wsb + alloc((size_t)NN*DD*2));
  float*  shb    = (float*) (wsb + alloc((size_t)EE*9*4));
  float*  dedge  = (float*) (wsb + alloc((size_t)EE*4));
  float*  P      = (float*) (wsb + alloc((size_t)NN*36*4));
  float2* sbuf   = (float2*)(wsb + alloc((size_t)EE*4*8));
  __hip_bfloat16* aggb = (__hip_bfloat16*)(wsb + alloc((size_t)NN*DD*2));
  __hip_bfloat16* tb480  = (__hip_bfloat16*)(wsb + alloc((size_t)NN*DD*2));
  __hip_bfloat16* tmp960 = (__hip_bfloat16*)(wsb + alloc((size_t)NN*960*2));
  float*  Tg     = (float*) (wsb + alloc((size_t)TSIZE*4));
  float*  Tl     = (float*) (wsb + alloc((size_t)LLAYERS*TSIZE*4*4));
  __hip_bfloat16* Wqkvt = (__hip_bfloat16*)(wsb + alloc((size_t)LLAYERS*1536*480*2));
  __hip_bfloat16* Wot   = (__hip_bfloat16*)(wsb + alloc((size_t)LLAYERS*512*480*2));
  __hip_bfloat16* Wf1t  = (__hip_bfloat16*)(wsb + alloc((size_t)LLAYERS*1024*480*2));
  __hip_bfloat16* Wf2t  = (__hip_bfloat16*)(wsb + alloc((size_t)LLAYERS*512*960*2));
  __hip_bfloat16* Wh1t  = (__hip_bfloat16*)(wsb + alloc((size_t)512*480*2));
  int* cnt     = (int*)(wsb + alloc((size_t)NN*4));
  int* row_ptr = (int*)(wsb + alloc((size_t)(NN+1)*4));
  int* cursor  = (int*)(wsb + alloc((size_t)NN*4));
  int* eid     = (int*)(wsb + alloc((size_t)EE*4));
  int* srcs    = (int*)(wsb + alloc((size_t)EE*4));
  (void)ws_size;

  auto tr = [&](const float* W, __hip_bfloat16* Wt, int K, int N, int Npad,
                long long lsW, long long lsT, int L) {
    dim3 g((Npad+31)/32, (K+31)/32, L);
    transpose_w_kernel<<<g, 256, 0, stream>>>(W, Wt, K, N, Npad, lsW, lsT);
  };

  tr(Wq,  Wqkvt + 0*512*480,    480, 480, 512, 480*480, 1536*480, LLAYERS);
  tr(Wk,  Wqkvt + 1*512*480,    480, 480, 512, 480*480, 1536*480, LLAYERS);
  tr(Wv,  Wqkvt + 2*512*480,    480, 480, 512, 480*480, 1536*480, LLAYERS);
  tr(Wo,  Wot,  480, 480, 512, 480*480, 512*480, LLAYERS);
  tr(Wf1, Wf1t, 480, 960, 1024, 480*960, 1024*480, LLAYERS);
  tr(Wf2, Wf2t, 960, 480, 512, 960*480, 512*960, LLAYERS);
  tr(Wh1, Wh1t, 480, 480, 512, 480*480, 512*480, 1);

  zero_kernel<<<(NN+255)/256, 256, 0, stream>>>(cnt, out);
  gather_x_kernel<<<640, 256, 0, stream>>>(atom_table, node_atom, x);
  edge_geom_kernel<<<(EE+255)/256, 256, 0, stream>>>(pos, edge_src, edge_dst, shb, dedge);
  hist_kernel<<<(EE+255)/256, 256, 0, stream>>>(edge_dst, cnt);
  scan_kernel<<<1, 1024, 0, stream>>>(cnt, row_ptr, cursor);
  scatter_kernel<<<(EE+255)/256, 256, 0, stream>>>(edge_src, edge_dst, cursor, eid, srcs);
  table_kernel<<<dim3(TSIZE/16, 1+LLAYERS), 1024, 0, stream>>>(Wd1, Wd2, Wd3, W1, W2, W3, Tg, Tl);
  deg_kernel<<<2500, 256, 0, stream>>>(dedge, shb, Tg, row_ptr, eid, Wdeg, x, xb);

  for (int l = 0; l < LLAYERS; ++l) {
    const __hip_bfloat16* Wqkvt_l = Wqkvt + (size_t)l*1536*480;
    const __hip_bfloat16* Wot_l   = Wot   + (size_t)l*512*480;
    const __hip_bfloat16* Wf1t_l  = Wf1t  + (size_t)l*1024*480;
    const __hip_bfloat16* Wf2t_l  = Wf2t  + (size_t)l*512*960;
    const float* Wsh_l = Wsh + (size_t)l*9*DD;
    const float* Tl_l  = Tl  + (size_t)l*TSIZE*4;

    gemm_bf16_kernel<0,2><<<dim3(12, 79), 512, 0, stream>>>(xb, Wqkvt_l, xq, xk, xv, NN, 480, 480);
    p_kernel<<<2500, 256, 0, stream>>>(xq, Wsh_l, P);
    coef_kernel<<<(EE+255)/256, 256, 0, stream>>>(eid, edge_dst, shb, dedge, Tl_l, P, sbuf);
    attn_kernel<<<2500, 256, 0, stream>>>(xq, xk, xv, sbuf, row_ptr, srcs, aggb);
    gemm64_bf16_kernel<0><<<dim3(8, 79), 256, 0, stream>>>(aggb, Wot_l, tb480, NN, 480, 480);
    ln_kernel<<<640, 256, 0, stream>>>(x, tb480, xb);
    gemm_bf16_kernel<1,1><<<dim3(8, 79), 512, 0, stream>>>(xb, Wf1t_l, tmp960, nullptr, nullptr, NN, 480, 960);
    gemm64_bf16_kernel<0><<<dim3(8, 79), 256, 0, stream>>>(tmp960, Wf2t_l, tb480, NN, 960, 480);
    ln_kernel<<<640, 256, 0, stream>>>(x, tb480, xb);
  }

  gemm64_bf16_kernel<1><<<dim3(8, 79), 256, 0, stream>>>(xb, Wh1t, tb480, NN, 480, 480);
  h2_kernel<<<160, 256, 0, stream>>>(tb480, Wh2, batch, out);
}